// Round 8
// baseline (230.710 us; speedup 1.0000x reference)
//
#include <hip/hip_runtime.h>
#include <stdint.h>

// B=8, C=128, N=4096 (64x64), GROUPS=8 (16 ch/group)
// Split-KV flash attention, 32x32x16 MFMA quadrants, max-free base-2 softmax.
// R17 = R16 with the P-swizzle key fixed: R16 computed pkey without masking to
//      3 bits, so ih>=2 leaked bit 3 into the slot XOR -> accesses displaced a
//      full row; row 127 went past the 80 KiB LDS block (absmax 0.44). Fix:
//      irow = ih*32+l31; pkey = (irow ^ (irow>>3)) & 7  (write AND read).
// R16 structure kept: 8-wave blocks (512 thr), i-tile 128, one shared K/V
// staging per block (gload_lds dbuf), LDS exactly 80 KiB -> 2 blocks/CU
// = 4 waves/SIMD. Reg prefetch dead (r5/r6, R10-12, R14). Rule #20 respected.

typedef __attribute__((ext_vector_type(8))) short short8;
typedef __attribute__((ext_vector_type(4))) float f32x4;
typedef __attribute__((ext_vector_type(16))) float f32x16;

#define MFMA_BF16(a, b, c) __builtin_amdgcn_mfma_f32_16x16x32_bf16((a), (b), (c), 0, 0, 0)
#define MFMA32(a, b, c) __builtin_amdgcn_mfma_f32_32x32x16_bf16((a), (b), (c), 0, 0, 0)
#define EXP2(x) __builtin_amdgcn_exp2f(x)

// (1/sqrt(128)) * log2(e) — folded into Q at k_qkv store time (softmax runs in base 2)
#define QSCALE 0.12751743f

__device__ __forceinline__ unsigned short f2bf(float f) {
    unsigned int u = __builtin_bit_cast(unsigned int, f);
    u += 0x7FFFu + ((u >> 16) & 1u);   // RNE (finite values only)
    return (unsigned short)(u >> 16);
}
__device__ __forceinline__ float bf2f(unsigned int lo16) {
    return __builtin_bit_cast(float, lo16 << 16);
}
__device__ __forceinline__ short8 ldg8(const unsigned short* p) {
    return __builtin_bit_cast(short8, *(const uint4*)p);
}
__device__ __forceinline__ unsigned int cvtpk(float lo, float hi) {
    unsigned int r;
    asm("v_cvt_pk_bf16_f32 %0, %1, %2" : "=v"(r) : "v"(lo), "v"(hi));
    return r;
}
__device__ __forceinline__ void gload16(const void* g, void* l) {
    __builtin_amdgcn_global_load_lds(
        (__attribute__((address_space(1))) void*)g,
        (__attribute__((address_space(3))) void*)l, 16, 0, 0);
}

// ---------------- Kernel 1: GroupNorm partial sums (atomic) + weight bf16 conv ------
__global__ __launch_bounds__(256) void k_pre(const float* __restrict__ x,
                                             float* __restrict__ sums,
                                             const float* __restrict__ qkv_w,
                                             const float* __restrict__ proj_w,
                                             unsigned short* __restrict__ wq,
                                             unsigned short* __restrict__ wp) {
    if (blockIdx.x >= 1024) {            // weight conversion: 64 blocks x 1024 elems
        int i = ((blockIdx.x - 1024) * 256 + threadIdx.x) * 4;
        const float* src; unsigned short* dst; int off;
        if (i < 49152) { src = qkv_w; dst = wq; off = i; }
        else           { src = proj_w; dst = wp; off = i - 49152; }
        float4 v = *(const float4*)(src + off);
        uint2 pk;
        pk.x = (unsigned int)f2bf(v.x) | ((unsigned int)f2bf(v.y) << 16);
        pk.y = (unsigned int)f2bf(v.z) | ((unsigned int)f2bf(v.w) << 16);
        *(uint2*)(dst + off) = pk;
        return;
    }
    int g     = blockIdx.x >> 4;         // 0..63 (b*8+gr); group slab contiguous
    int slice = blockIdx.x & 15;
    const float* p = x + (size_t)g * 65536 + slice * 4096;
    float s = 0.f, sq = 0.f;
#pragma unroll
    for (int i = 0; i < 4; ++i) {
        float4 v = *(const float4*)(p + threadIdx.x * 4 + i * 1024);
        s  += v.x + v.y + v.z + v.w;
        sq += v.x*v.x + v.y*v.y + v.z*v.z + v.w*v.w;
    }
#pragma unroll
    for (int m = 1; m < 64; m <<= 1) { s += __shfl_xor(s, m, 64); sq += __shfl_xor(sq, m, 64); }
    __shared__ float ss[4], ssq[4];
    int w = threadIdx.x >> 6;
    if ((threadIdx.x & 63) == 0) { ss[w] = s; ssq[w] = sq; }
    __syncthreads();
    if (threadIdx.x == 0) {
        atomicAdd(&sums[g * 2],     ss[0] + ss[1] + ss[2] + ss[3]);
        atomicAdd(&sums[g * 2 + 1], ssq[0] + ssq[1] + ssq[2] + ssq[3]);
    }
}

// ---------------- Kernel 2: fused GroupNorm-apply + QKV GEMM ----------------
// Q (pre-scaled by QSCALE), K as bf16 [b][n][c]; V as bf16 [b][c][n].
// V tiles computed transposed (MFMA(bfrag, af) -> D[n][c]) -> packed 8B global stores.
__global__ __launch_bounds__(256) void k_qkv(const float* __restrict__ x,
                                             const float* __restrict__ sums,
                                             const float* __restrict__ gn_w,
                                             const float* __restrict__ gn_b,
                                             const unsigned short* __restrict__ wq,
                                             const float* __restrict__ qkv_b,
                                             unsigned short* __restrict__ q_ws,
                                             unsigned short* __restrict__ k_ws,
                                             unsigned short* __restrict__ v_ws) {
    __shared__ unsigned short h_lds[64][136];   // [n][c], +8 pad
    const int tid  = threadIdx.x;
    const int b    = blockIdx.x >> 6;
    const int n0   = (blockIdx.x & 63) << 6;
    const int lane = tid & 63, wave = tid >> 6;
    const int l15  = lane & 15, q4 = lane >> 4;

    // normalize x tile -> bf16 -> h_lds[n][c]
    {
        int cb = tid >> 4;            // 0..15
        int nn = (tid & 15) << 2;     // 0..60
#pragma unroll
        for (int k = 0; k < 8; ++k) {
            int c = cb + (k << 4);
            float4 v = *(const float4*)(x + ((size_t)(b * 128 + c) << 12) + n0 + nn);
            int g = c >> 4;
            float ts = sums[(b * 8 + g) * 2];
            float tq = sums[(b * 8 + g) * 2 + 1];
            float mean = ts * (1.f / 65536.f);
            float var  = tq * (1.f / 65536.f) - mean * mean;
            float rstd = rsqrtf(var + 1e-5f);
            float ga = gn_w[c] * rstd;
            float be = gn_b[c] - mean * ga;
            h_lds[nn + 0][c] = f2bf(v.x * ga + be);
            h_lds[nn + 1][c] = f2bf(v.y * ga + be);
            h_lds[nn + 2][c] = f2bf(v.z * ga + be);
            h_lds[nn + 3][c] = f2bf(v.w * ga + be);
        }
    }
    __syncthreads();

    short8 bfrag[4][4];               // h[n][c]: as B (k=c, n=l15) or as A (m=n, k=c)
#pragma unroll
    for (int nt = 0; nt < 4; ++nt)
#pragma unroll
        for (int ks = 0; ks < 4; ++ks)
            bfrag[nt][ks] = *(const short8*)&h_lds[nt * 16 + l15][ks * 32 + q4 * 8];

#pragma unroll
    for (int ot = 0; ot < 6; ++ot) {
        int o0 = wave * 96 + ot * 16;                 // 16-row tile is purely Q, K, or V
        short8 af[4];                                 // w[o][c]: as A (m=o) or as B (n=o)
#pragma unroll
        for (int ks = 0; ks < 4; ++ks)
            af[ks] = ldg8(wq + (size_t)(o0 + l15) * 128 + ks * 32 + q4 * 8);

        if (o0 < 256) {               // Q or K: D[row=o(reg)][col=n=l15] -> [n][c] layout
            float bias[4];
#pragma unroll
            for (int r = 0; r < 4; ++r) bias[r] = qkv_b[o0 + q4 * 4 + r];
            float qs = (o0 < 128) ? QSCALE : 1.0f;
#pragma unroll
            for (int nt = 0; nt < 4; ++nt) {
                f32x4 acc = {0.f, 0.f, 0.f, 0.f};
#pragma unroll
                for (int ks = 0; ks < 4; ++ks)
                    acc = MFMA_BF16(af[ks], bfrag[nt][ks], acc);
                int n = n0 + nt * 16 + l15;
                unsigned short* dst = (o0 < 128) ? q_ws : k_ws;
                int oo = (o0 < 128) ? o0 : (o0 - 128);
                unsigned int lo = (unsigned int)f2bf((acc[0] + bias[0]) * qs) |
                                  ((unsigned int)f2bf((acc[1] + bias[1]) * qs) << 16);
                unsigned int hi = (unsigned int)f2bf((acc[2] + bias[2]) * qs) |
                                  ((unsigned int)f2bf((acc[3] + bias[3]) * qs) << 16);
                uint2 pk; pk.x = lo; pk.y = hi;
                *(uint2*)&dst[((size_t)(b * 4096 + n) << 7) + oo + q4 * 4] = pk;
            }
        } else {                      // V transposed: D[row=n(reg)][col=c=l15] -> [c][n]
            int c = o0 - 256 + l15;
            float vb = qkv_b[o0 + l15];
            unsigned short* vrow = v_ws + ((size_t)(b * 128 + c) << 12) + n0;
#pragma unroll
            for (int nt = 0; nt < 4; ++nt) {
                f32x4 acc = {0.f, 0.f, 0.f, 0.f};
#pragma unroll
                for (int ks = 0; ks < 4; ++ks)
                    acc = MFMA_BF16(bfrag[nt][ks], af[ks], acc);
                // n = nt*16 + q4*4 + r (4 consecutive) at fixed c -> packed 8B store
                unsigned int lo = (unsigned int)f2bf(acc[0] + vb) |
                                  ((unsigned int)f2bf(acc[1] + vb) << 16);
                unsigned int hi = (unsigned int)f2bf(acc[2] + vb) |
                                  ((unsigned int)f2bf(acc[3] + vb) << 16);
                uint2 pk; pk.x = lo; pk.y = hi;
                *(uint2*)&vrow[nt * 16 + q4 * 4] = pk;
            }
        }
    }
}

// ---------------- Kernel 3: flash attention partial (split-KV, 8 waves, i=128) ----
// block = 512 threads / 8 waves = (b, i-tile(128), chunk); chunk covers 1024 j.
// wave = (ih in 0..3, jh in 0..1). Per wave: QK quadrant S^T (j in regs, i in
// lane), P exchange through swizzled P_lds, PV with acc[2] (c-half by jh).
// K/V staged ONCE per block via gload_lds dbuf (serves all 128 i rows).
// Swizzles (content at LDS slot sp of row r = global slot sp ^ key(r)):
//   K: key = r & 15                 (16B slots of 256B row)   [R2/R3-verified]
//   V: key = (r ^ (r>>3)) & 7       (16B slots of 128B row)
//   P: key = (i ^ (i>>3)) & 7       (16B slots of 128B row)  [R17: & 7 FIXED]
__global__ __launch_bounds__(512, 4) void k_attn_part(const unsigned short* __restrict__ q_ws,
                                                      const unsigned short* __restrict__ k_ws,
                                                      const unsigned short* __restrict__ v_ws,
                                                      unsigned short* __restrict__ o_part,
                                                      float* __restrict__ ml) {
    __shared__ unsigned short K0[64][128];      // 16 KB
    __shared__ unsigned short K1[64][128];      // 16 KB
    __shared__ unsigned short V0[128][64];      // 16 KB
    __shared__ unsigned short V1[128][64];      // 16 KB
    __shared__ unsigned short P_lds[128][64];   // 16 KB  -> total 80 KiB exactly

    const int tid   = threadIdx.x;              // 0..511
    const int chunk = blockIdx.x & 3;
    const int tile  = (blockIdx.x >> 2) & 31;
    const int b     = blockIdx.x >> 7;
    const int i0    = tile << 7;                // 128-row i-tile
    const int lane  = tid & 63, wave = tid >> 6;
    const int ih    = wave >> 1, jh = wave & 1; // jh doubles as c-half in PV
    const int l31   = lane & 31, h = lane >> 5;

    // Q frags (pre-scaled by QSCALE): lane holds i = ih*32+l31, k=c=ks*16+h*8+e
    short8 qf[8];
    {
        const unsigned short* qp =
            q_ws + ((size_t)(b * 4096 + i0 + ih * 32 + l31) << 7) + h * 8;
#pragma unroll
        for (int ks = 0; ks < 8; ++ks) qf[ks] = ldg8(qp + ks * 16);
    }

    f32x16 acc[2];                           // O[i(reg)][c = jh*64 + ct*32 + l31]
#pragma unroll
    for (int e = 0; e < 16; ++e) { acc[0][e] = 0.f; acc[1][e] = 0.f; }
    float l_run = 0.f;

    // K staging: chunk c = q*512 + tid; dest linear; src slot = (c&15)^(row&15)
    const unsigned short* kbase = k_ws + ((size_t)b << 19) + ((size_t)chunk << 17);
    int ksrc[2];
#pragma unroll
    for (int q = 0; q < 2; ++q) {
        int c   = q * 512 + tid;
        int row = c >> 4;
        ksrc[q] = row * 16 + ((c & 15) ^ (row & 15));
    }
    // V staging: chunk c = q*512 + tid; row = c>>3 = q*64 + (tid>>3);
    // src s8 = (c&7) ^ key(row), key(row) = (row ^ (row>>3)) & 7 = ((tid>>3)&7) ^ wave
    const unsigned short* vlane = v_ws + ((size_t)b << 19) +
        ((size_t)(tid >> 3) << 12) + (chunk << 10) +
        ((((tid & 7) ^ ((tid >> 3) & 7) ^ wave)) << 3);

#define STAGE(T, KD, VD)                                                              \
  do {                                                                                \
    _Pragma("unroll")                                                                 \
    for (int q = 0; q < 2; ++q)                                                       \
      gload16(kbase + (size_t)(T) * 8192 + ksrc[q] * 8,                               \
              (char*)(&KD[0][0]) + q * 8192 + wave * 1024);                           \
    _Pragma("unroll")                                                                 \
    for (int q = 0; q < 2; ++q)                                                       \
      gload16(vlane + (size_t)q * 262144 + (T) * 64,                                  \
              (char*)(&VD[0][0]) + q * 8192 + wave * 1024);                           \
  } while (0)

    const int krow = jh * 32 + l31;
    const int ksw  = l31 & 15;                    // krow & 15
    const int vk   = (l31 & 7) ^ (l31 >> 3);      // V key base (^ (ct<<2) per ct)
    const int irow = ih * 32 + l31;               // this lane's P row
    const int pkey = (irow ^ (irow >> 3)) & 7;    // P key  [R17 FIX: masked to 3 bits]

    // prologue: prefetch tile 0 -> buf0 (drained at first barrier; one-time cost)
    STAGE(0, K0, V0);

#define ATTN_ITER(IT, KR, VR, KP, VP)                                                 \
  do {                                                                                \
    __syncthreads(); /* A: buf(IT) loads visible; prev iter's LDS reads done */       \
    if ((IT) < 15) STAGE((IT) + 1, KP, VP);   /* drains at NEXT barrier A: hidden */  \
    f32x16 s; /* S^T quadrant: row j=(r&3)+8(r>>2)+4h (+jh*32), col i (lane) */       \
    _Pragma("unroll")                                                                 \
    for (int e = 0; e < 16; ++e) s[e] = 0.f;                                          \
    _Pragma("unroll")                                                                 \
    for (int ks = 0; ks < 8; ++ks) {                                                  \
      short8 kf = *(const short8*)&KR[krow][((ks * 2 + h) ^ ksw) << 3];               \
      s = MFMA32(kf, qf[ks], s);                                                      \
    }                                                                                 \
    float pv[16]; /* max-free base-2 softmax */                                       \
    _Pragma("unroll")                                                                 \
    for (int e = 0; e < 16; ++e) pv[e] = EXP2(fminf(s[e], 30.f));                     \
    l_run += (((pv[0] + pv[1]) + (pv[2] + pv[3])) +                                   \
              ((pv[4] + pv[5]) + (pv[6] + pv[7]))) +                                  \
             (((pv[8] + pv[9]) + (pv[10] + pv[11])) +                                 \
              ((pv[12] + pv[13]) + (pv[14] + pv[15])));                               \
    {                                                                                 \
      char* prow = (char*)&P_lds[irow][0];                                            \
      _Pragma("unroll")                                                               \
      for (int rr = 0; rr < 4; ++rr) {                                                \
        uint2 pk;                                                                     \
        pk.x = cvtpk(pv[rr * 4 + 0], pv[rr * 4 + 1]);                                 \
        pk.y = cvtpk(pv[rr * 4 + 2], pv[rr * 4 + 3]);                                 \
        *(uint2*)(prow + ((((jh << 2) + rr) ^ pkey) << 4) + (h << 3)) = pk;           \
      }                                                                               \
    }                                                                                 \
    __syncthreads(); /* B: P visible */                                               \
    _Pragma("unroll")                                                                 \
    for (int ks = 0; ks < 4; ++ks) {                                                  \
      short8 pf = *(const short8*)((const char*)&P_lds[irow][0] +                     \
                                   (((ks * 2 + h) ^ pkey) << 4));                     \
      _Pragma("unroll")                                                               \
      for (int ct = 0; ct < 2; ++ct) {                                                \
        short8 vf = *(const short8*)&VR[jh * 64 + ct * 32 + l31]                      \
                        [((ks * 2 + h) ^ vk ^ (ct << 2)) << 3];                       \
        acc[ct] = MFMA32(pf, vf, acc[ct]);                                            \
      }                                                                               \
    }                                                                                 \
  } while (0)

    for (int ib = 0; ib < 8; ++ib) {
        ATTN_ITER(ib * 2,     K0, V0, K1, V1);
        ATTN_ITER(ib * 2 + 1, K1, V1, K0, V0);
    }
#undef ATTN_ITER
#undef STAGE

    // epilogue: combine row sums (h via shfl, jh via LDS overlay on K0), store
    __syncthreads();                                 // all loop LDS reads done
    float* Lp = (float*)(&K0[0][0]);                 // [jh*128 + i], 1 KB of K0
    float l2 = l_run + __shfl_xor(l_run, 32);        // h-halves: disjoint j, same i
    if (h == 0) Lp[jh * 128 + irow] = l2;
    __syncthreads();

    float rl[16];
#pragma unroll
    for (int r = 0; r < 16; ++r) {
        int il = (r & 3) + ((r >> 2) << 3) + (h << 2);
        rl[r] = 1.0f / (Lp[ih * 32 + il] + Lp[128 + ih * 32 + il]);
    }
#pragma unroll
    for (int ct = 0; ct < 2; ++ct)
#pragma unroll
        for (int r = 0; r < 16; ++r) {
            int row = ih * 32 + (r & 3) + ((r >> 2) << 3) + (h << 2);
            // o_part layout: [b][i 4096][chunk 4][c 128]
            o_part[(((size_t)(b * 4096 + i0 + row) * 4 + chunk) << 7) +
                   jh * 64 + ct * 32 + l31] = f2bf(acc[ct][r] * rl[r]);
        }
    if (tid < 128) {
        // ml layout: [b][i 4096][chunk 4]
        ml[(b * 4096 + i0 + tid) * 4 + chunk] = __log2f(Lp[tid] + Lp[128 + tid]);
    }
}

// ---------------- Kernel 4: merge partials + proj GEMM + bias + residual ----------
__global__ __launch_bounds__(256) void k_merge_proj(const unsigned short* __restrict__ o_part,
                                                    const float* __restrict__ ml,
                                                    const float* __restrict__ x,
                                                    const unsigned short* __restrict__ wp,
                                                    const float* __restrict__ proj_b,
                                                    float* __restrict__ out) {
    __shared__ unsigned short O_lds[64][136];
    __shared__ float wgt[64][4];
    const int tid  = threadIdx.x;
    const int b    = blockIdx.x >> 6;
    const int tile = blockIdx.x & 63;
    const int i0   = tile << 6;
    const int lane = tid & 63, wave = tid >> 6;
    const int l15  = lane & 15, q4 = lane >> 4;

    if (tid < 64) {
        size_t mb = (size_t)(b * 4096 + i0 + tid) * 4;
        float m0 = ml[mb + 0], m1 = ml[mb + 1], m2 = ml[mb + 2], m3 = ml[mb + 3];
        float M = fmaxf(fmaxf(m0, m1), fmaxf(m2, m3));
        float w0 = EXP2(m0 - M), w1 = EXP2(m1 - M), w2 = EXP2(m2 - M), w3 = EXP2(m3 - M);
        float rW = 1.0f / (w0 + w1 + w2 + w3);
        wgt[tid][0] = w0 * rW; wgt[tid][1] = w1 * rW;
        wgt[tid][2] = w2 * rW; wgt[tid][3] = w3 * rW;
    }
    __syncthreads();

    {   // weighted merge: thread t -> row n=t>>2, 32-c quarter q=t&3
        int n = tid >> 2, q = tid & 3;
        float w[4];
#pragma unroll
        for (int ch = 0; ch < 4; ++ch) w[ch] = wgt[n][ch];
        size_t rbase = ((size_t)(b * 4096 + i0 + n) * 4) << 7;   // row's 4 partials
#pragma unroll
        for (int g = 0; g < 4; ++g) {             // 8 c per group
            float acc[8];
#pragma unroll
            for (int e = 0; e < 8; ++e) acc[e] = 0.f;
#pragma unroll
            for (int ch = 0; ch < 4; ++ch) {
                const unsigned short* p = o_part + rbase + (ch << 7) + q * 32 + g * 8;
                uint4 v = *(const uint4*)p;
                float wc = w[ch];
                acc[0] += wc * bf2f(v.x & 0xFFFF); acc[1] += wc * bf2f(v.x >> 16);
                acc[2] += wc * bf2f(v.y & 0xFFFF); acc[3] += wc * bf2f(v.y >> 16);
                acc[4] += wc * bf2f(v.z & 0xFFFF); acc[5] += wc * bf2f(v.z >> 16);
                acc[6] += wc * bf2f(v.w & 0xFFFF); acc[7] += wc * bf2f(v.w >> 16);
            }
            uint4 pk;
            pk.x = (unsigned int)f2bf(acc[0]) | ((unsigned int)f2bf(acc[1]) << 16);
            pk.y = (unsigned int)f2bf(acc[2]) | ((unsigned int)f2bf(acc[3]) << 16);
            pk.z = (unsigned int)f2bf(acc[4]) | ((unsigned int)f2bf(acc[5]) << 16);
            pk.w = (unsigned int)f2bf(acc[6]) | ((unsigned int)f2bf(acc[7]) << 16);
            *(uint4*)&O_lds[n][q * 32 + g * 8] = pk;
        }
    }
    __syncthreads();

    // proj GEMM: out[o][n] = sum_c proj_w[o][c] * O[n][c] + proj_b + x
    short8 bfrag[4][4];
#pragma unroll
    for (int nt = 0; nt < 4; ++nt)
#pragma unroll
        for (int ks = 0; ks < 4; ++ks)
            bfrag[nt][ks] = *(const short8*)&O_lds[nt * 16 + l15][ks * 32 + q4 * 8];

#pragma unroll
    for (int ot = 0; ot < 2; ++ot) {
        int o0 = wave * 32 + ot * 16;
        short8 af[4];
#pragma unroll
        for (int ks = 0; ks < 4; ++ks)
            af[ks] = ldg8(wp + (size_t)(o0 + l15) * 128 + ks * 32 + q4 * 8);
        float pb[4];
#pragma unroll
        for (int r = 0; r < 4; ++r) pb[r] = proj_b[o0 + q4 * 4 + r];

#pragma unroll
        for (int nt = 0; nt < 4; ++nt) {
            f32x4 acc = {0.f, 0.f, 0.f, 0.f};
#pragma unroll
            for (int ks = 0; ks < 4; ++ks)
                acc = MFMA_BF16(af[ks], bfrag[nt][ks], acc);
#pragma unroll
            for (int r = 0; r < 4; ++r) {
                size_t idx = ((size_t)(b * 128 + o0 + q4 * 4 + r) << 12) + i0 + nt * 16 + l15;
                out[idx] = x[idx] + acc[r] + pb[r];
            }
        }
    }
}

// ---------------- launch ----------------
extern "C" void kernel_launch(void* const* d_in, const int* in_sizes, int n_in,
                              void* d_out, int out_size, void* d_ws, size_t ws_size,
                              hipStream_t stream) {
    const float* x      = (const float*)d_in[0];
    const float* gn_w   = (const float*)d_in[1];
    const float* gn_b   = (const float*)d_in[2];
    const float* qkv_w  = (const float*)d_in[3];
    const float* qkv_b  = (const float*)d_in[4];
    const float* proj_w = (const float*)d_in[5];
    const float* proj_b = (const float*)d_in[6];
    float* out = (float*)d_out;

    char* ws = (char*)d_ws;
    float* sums           = (float*)ws;                              // 512 B (zeroed below)
    unsigned short* wq    = (unsigned short*)(ws + 4096);            // 96 KB
    unsigned short* wp    = (unsigned short*)(ws + 4096 + 98304);    // 32 KB
    unsigned short* q_ws  = (unsigned short*)(ws + ((size_t)1  << 20));  // 8 MB
    unsigned short* k_ws  = (unsigned short*)(ws + ((size_t)9  << 20));  // 8 MB
    unsigned short* v_ws  = (unsigned short*)(ws + ((size_t)17 << 20));  // 8 MB
    unsigned short* o_part= (unsigned short*)(ws + ((size_t)25 << 20));  // 32 MB
    float* ml             = (float*)(ws + ((size_t)57 << 20));           // 512 KB

    hipMemsetAsync(sums, 0, 512, stream);
    k_pre<<<1088, 256, 0, stream>>>(x, sums, qkv_w, proj_w, wq, wp);
    k_qkv<<<512, 256, 0, stream>>>(x, sums, gn_w, gn_b, wq, qkv_b, q_ws, k_ws, v_ws);
    k_attn_part<<<1024, 512, 0, stream>>>(q_ws, k_ws, v_ws, o_part, ml);
    k_merge_proj<<<512, 256, 0, stream>>>(o_part, ml, x, wp, proj_b, out);
}

// Round 10
// 196.175 us; speedup vs baseline: 1.1760x; 1.1760x over previous
//
#include <hip/hip_runtime.h>
#include <stdint.h>

// B=8, C=128, N=4096 (64x64), GROUPS=8 (16 ch/group)
// Split-KV flash attention, 32x32x16 MFMA quadrants, max-free base-2 softmax.
// R18 = R17 with __launch_bounds__(512, 2) instead of (512, 4).
//      R17's (512,4) capped the UNIFIED VGPR+AGPR budget at 128/thread; acc+qf
//      consumed it and the rest (s, pv, addressing) spilled -> 90 MB/iter
//      scratch traffic (WRITE 123 MB, VGPR_Count 64), 130 us. The register cap
//      was unnecessary: LDS (80 KiB/block) already limits residency to
//      2 blocks/CU = 4 waves/SIMD. (512,2) keeps that occupancy with a 256-reg
//      budget. Everything else identical to R17 (verified correct).
//      [Resubmit: previous round was an infra failure, kernel never ran.]

typedef __attribute__((ext_vector_type(8))) short short8;
typedef __attribute__((ext_vector_type(4))) float f32x4;
typedef __attribute__((ext_vector_type(16))) float f32x16;

#define MFMA_BF16(a, b, c) __builtin_amdgcn_mfma_f32_16x16x32_bf16((a), (b), (c), 0, 0, 0)
#define MFMA32(a, b, c) __builtin_amdgcn_mfma_f32_32x32x16_bf16((a), (b), (c), 0, 0, 0)
#define EXP2(x) __builtin_amdgcn_exp2f(x)

// (1/sqrt(128)) * log2(e) — folded into Q at k_qkv store time (softmax runs in base 2)
#define QSCALE 0.12751743f

__device__ __forceinline__ unsigned short f2bf(float f) {
    unsigned int u = __builtin_bit_cast(unsigned int, f);
    u += 0x7FFFu + ((u >> 16) & 1u);   // RNE (finite values only)
    return (unsigned short)(u >> 16);
}
__device__ __forceinline__ float bf2f(unsigned int lo16) {
    return __builtin_bit_cast(float, lo16 << 16);
}
__device__ __forceinline__ short8 ldg8(const unsigned short* p) {
    return __builtin_bit_cast(short8, *(const uint4*)p);
}
__device__ __forceinline__ unsigned int cvtpk(float lo, float hi) {
    unsigned int r;
    asm("v_cvt_pk_bf16_f32 %0, %1, %2" : "=v"(r) : "v"(lo), "v"(hi));
    return r;
}
__device__ __forceinline__ void gload16(const void* g, void* l) {
    __builtin_amdgcn_global_load_lds(
        (__attribute__((address_space(1))) void*)g,
        (__attribute__((address_space(3))) void*)l, 16, 0, 0);
}

// ---------------- Kernel 1: GroupNorm partial sums (atomic) + weight bf16 conv ------
__global__ __launch_bounds__(256) void k_pre(const float* __restrict__ x,
                                             float* __restrict__ sums,
                                             const float* __restrict__ qkv_w,
                                             const float* __restrict__ proj_w,
                                             unsigned short* __restrict__ wq,
                                             unsigned short* __restrict__ wp) {
    if (blockIdx.x >= 1024) {            // weight conversion: 64 blocks x 1024 elems
        int i = ((blockIdx.x - 1024) * 256 + threadIdx.x) * 4;
        const float* src; unsigned short* dst; int off;
        if (i < 49152) { src = qkv_w; dst = wq; off = i; }
        else           { src = proj_w; dst = wp; off = i - 49152; }
        float4 v = *(const float4*)(src + off);
        uint2 pk;
        pk.x = (unsigned int)f2bf(v.x) | ((unsigned int)f2bf(v.y) << 16);
        pk.y = (unsigned int)f2bf(v.z) | ((unsigned int)f2bf(v.w) << 16);
        *(uint2*)(dst + off) = pk;
        return;
    }
    int g     = blockIdx.x >> 4;         // 0..63 (b*8+gr); group slab contiguous
    int slice = blockIdx.x & 15;
    const float* p = x + (size_t)g * 65536 + slice * 4096;
    float s = 0.f, sq = 0.f;
#pragma unroll
    for (int i = 0; i < 4; ++i) {
        float4 v = *(const float4*)(p + threadIdx.x * 4 + i * 1024);
        s  += v.x + v.y + v.z + v.w;
        sq += v.x*v.x + v.y*v.y + v.z*v.z + v.w*v.w;
    }
#pragma unroll
    for (int m = 1; m < 64; m <<= 1) { s += __shfl_xor(s, m, 64); sq += __shfl_xor(sq, m, 64); }
    __shared__ float ss[4], ssq[4];
    int w = threadIdx.x >> 6;
    if ((threadIdx.x & 63) == 0) { ss[w] = s; ssq[w] = sq; }
    __syncthreads();
    if (threadIdx.x == 0) {
        atomicAdd(&sums[g * 2],     ss[0] + ss[1] + ss[2] + ss[3]);
        atomicAdd(&sums[g * 2 + 1], ssq[0] + ssq[1] + ssq[2] + ssq[3]);
    }
}

// ---------------- Kernel 2: fused GroupNorm-apply + QKV GEMM ----------------
// Q (pre-scaled by QSCALE), K as bf16 [b][n][c]; V as bf16 [b][c][n].
// V tiles computed transposed (MFMA(bfrag, af) -> D[n][c]) -> packed 8B global stores.
__global__ __launch_bounds__(256) void k_qkv(const float* __restrict__ x,
                                             const float* __restrict__ sums,
                                             const float* __restrict__ gn_w,
                                             const float* __restrict__ gn_b,
                                             const unsigned short* __restrict__ wq,
                                             const float* __restrict__ qkv_b,
                                             unsigned short* __restrict__ q_ws,
                                             unsigned short* __restrict__ k_ws,
                                             unsigned short* __restrict__ v_ws) {
    __shared__ unsigned short h_lds[64][136];   // [n][c], +8 pad
    const int tid  = threadIdx.x;
    const int b    = blockIdx.x >> 6;
    const int n0   = (blockIdx.x & 63) << 6;
    const int lane = tid & 63, wave = tid >> 6;
    const int l15  = lane & 15, q4 = lane >> 4;

    // normalize x tile -> bf16 -> h_lds[n][c]
    {
        int cb = tid >> 4;            // 0..15
        int nn = (tid & 15) << 2;     // 0..60
#pragma unroll
        for (int k = 0; k < 8; ++k) {
            int c = cb + (k << 4);
            float4 v = *(const float4*)(x + ((size_t)(b * 128 + c) << 12) + n0 + nn);
            int g = c >> 4;
            float ts = sums[(b * 8 + g) * 2];
            float tq = sums[(b * 8 + g) * 2 + 1];
            float mean = ts * (1.f / 65536.f);
            float var  = tq * (1.f / 65536.f) - mean * mean;
            float rstd = rsqrtf(var + 1e-5f);
            float ga = gn_w[c] * rstd;
            float be = gn_b[c] - mean * ga;
            h_lds[nn + 0][c] = f2bf(v.x * ga + be);
            h_lds[nn + 1][c] = f2bf(v.y * ga + be);
            h_lds[nn + 2][c] = f2bf(v.z * ga + be);
            h_lds[nn + 3][c] = f2bf(v.w * ga + be);
        }
    }
    __syncthreads();

    short8 bfrag[4][4];               // h[n][c]: as B (k=c, n=l15) or as A (m=n, k=c)
#pragma unroll
    for (int nt = 0; nt < 4; ++nt)
#pragma unroll
        for (int ks = 0; ks < 4; ++ks)
            bfrag[nt][ks] = *(const short8*)&h_lds[nt * 16 + l15][ks * 32 + q4 * 8];

#pragma unroll
    for (int ot = 0; ot < 6; ++ot) {
        int o0 = wave * 96 + ot * 16;                 // 16-row tile is purely Q, K, or V
        short8 af[4];                                 // w[o][c]: as A (m=o) or as B (n=o)
#pragma unroll
        for (int ks = 0; ks < 4; ++ks)
            af[ks] = ldg8(wq + (size_t)(o0 + l15) * 128 + ks * 32 + q4 * 8);

        if (o0 < 256) {               // Q or K: D[row=o(reg)][col=n=l15] -> [n][c] layout
            float bias[4];
#pragma unroll
            for (int r = 0; r < 4; ++r) bias[r] = qkv_b[o0 + q4 * 4 + r];
            float qs = (o0 < 128) ? QSCALE : 1.0f;
#pragma unroll
            for (int nt = 0; nt < 4; ++nt) {
                f32x4 acc = {0.f, 0.f, 0.f, 0.f};
#pragma unroll
                for (int ks = 0; ks < 4; ++ks)
                    acc = MFMA_BF16(af[ks], bfrag[nt][ks], acc);
                int n = n0 + nt * 16 + l15;
                unsigned short* dst = (o0 < 128) ? q_ws : k_ws;
                int oo = (o0 < 128) ? o0 : (o0 - 128);
                unsigned int lo = (unsigned int)f2bf((acc[0] + bias[0]) * qs) |
                                  ((unsigned int)f2bf((acc[1] + bias[1]) * qs) << 16);
                unsigned int hi = (unsigned int)f2bf((acc[2] + bias[2]) * qs) |
                                  ((unsigned int)f2bf((acc[3] + bias[3]) * qs) << 16);
                uint2 pk; pk.x = lo; pk.y = hi;
                *(uint2*)&dst[((size_t)(b * 4096 + n) << 7) + oo + q4 * 4] = pk;
            }
        } else {                      // V transposed: D[row=n(reg)][col=c=l15] -> [c][n]
            int c = o0 - 256 + l15;
            float vb = qkv_b[o0 + l15];
            unsigned short* vrow = v_ws + ((size_t)(b * 128 + c) << 12) + n0;
#pragma unroll
            for (int nt = 0; nt < 4; ++nt) {
                f32x4 acc = {0.f, 0.f, 0.f, 0.f};
#pragma unroll
                for (int ks = 0; ks < 4; ++ks)
                    acc = MFMA_BF16(bfrag[nt][ks], af[ks], acc);
                // n = nt*16 + q4*4 + r (4 consecutive) at fixed c -> packed 8B store
                unsigned int lo = (unsigned int)f2bf(acc[0] + vb) |
                                  ((unsigned int)f2bf(acc[1] + vb) << 16);
                unsigned int hi = (unsigned int)f2bf(acc[2] + vb) |
                                  ((unsigned int)f2bf(acc[3] + vb) << 16);
                uint2 pk; pk.x = lo; pk.y = hi;
                *(uint2*)&vrow[nt * 16 + q4 * 4] = pk;
            }
        }
    }
}

// ---------------- Kernel 3: flash attention partial (split-KV, 8 waves, i=128) ----
// block = 512 threads / 8 waves = (b, i-tile(128), chunk); chunk covers 1024 j.
// wave = (ih in 0..3, jh in 0..1). Per wave: QK quadrant S^T (j in regs, i in
// lane), P exchange through swizzled P_lds, PV with acc[2] (c-half by jh).
// K/V staged ONCE per block via gload_lds dbuf (serves all 128 i rows).
// Swizzles (content at LDS slot sp of row r = global slot sp ^ key(r)):
//   K: key = r & 15                 (16B slots of 256B row)   [R2/R3-verified]
//   V: key = (r ^ (r>>3)) & 7       (16B slots of 128B row)
//   P: key = (i ^ (i>>3)) & 7       (16B slots of 128B row)
// launch_bounds (512,2): LDS (80 KiB) limits to 2 blocks/CU = 4 waves/SIMD;
// do NOT cap registers below need (R17 lesson: (512,4) -> 128-reg cap -> spill).
__global__ __launch_bounds__(512, 2) void k_attn_part(const unsigned short* __restrict__ q_ws,
                                                      const unsigned short* __restrict__ k_ws,
                                                      const unsigned short* __restrict__ v_ws,
                                                      unsigned short* __restrict__ o_part,
                                                      float* __restrict__ ml) {
    __shared__ unsigned short K0[64][128];      // 16 KB
    __shared__ unsigned short K1[64][128];      // 16 KB
    __shared__ unsigned short V0[128][64];      // 16 KB
    __shared__ unsigned short V1[128][64];      // 16 KB
    __shared__ unsigned short P_lds[128][64];   // 16 KB  -> total 80 KiB exactly

    const int tid   = threadIdx.x;              // 0..511
    const int chunk = blockIdx.x & 3;
    const int tile  = (blockIdx.x >> 2) & 31;
    const int b     = blockIdx.x >> 7;
    const int i0    = tile << 7;                // 128-row i-tile
    const int lane  = tid & 63, wave = tid >> 6;
    const int ih    = wave >> 1, jh = wave & 1; // jh doubles as c-half in PV
    const int l31   = lane & 31, h = lane >> 5;

    // Q frags (pre-scaled by QSCALE): lane holds i = ih*32+l31, k=c=ks*16+h*8+e
    short8 qf[8];
    {
        const unsigned short* qp =
            q_ws + ((size_t)(b * 4096 + i0 + ih * 32 + l31) << 7) + h * 8;
#pragma unroll
        for (int ks = 0; ks < 8; ++ks) qf[ks] = ldg8(qp + ks * 16);
    }

    f32x16 acc[2];                           // O[i(reg)][c = jh*64 + ct*32 + l31]
#pragma unroll
    for (int e = 0; e < 16; ++e) { acc[0][e] = 0.f; acc[1][e] = 0.f; }
    float l_run = 0.f;

    // K staging: chunk c = q*512 + tid; dest linear; src slot = (c&15)^(row&15)
    const unsigned short* kbase = k_ws + ((size_t)b << 19) + ((size_t)chunk << 17);
    int ksrc[2];
#pragma unroll
    for (int q = 0; q < 2; ++q) {
        int c   = q * 512 + tid;
        int row = c >> 4;
        ksrc[q] = row * 16 + ((c & 15) ^ (row & 15));
    }
    // V staging: chunk c = q*512 + tid; row = c>>3 = q*64 + (tid>>3);
    // src s8 = (c&7) ^ key(row), key(row) = (row ^ (row>>3)) & 7 = ((tid>>3)&7) ^ wave
    const unsigned short* vlane = v_ws + ((size_t)b << 19) +
        ((size_t)(tid >> 3) << 12) + (chunk << 10) +
        ((((tid & 7) ^ ((tid >> 3) & 7) ^ wave)) << 3);

#define STAGE(T, KD, VD)                                                              \
  do {                                                                                \
    _Pragma("unroll")                                                                 \
    for (int q = 0; q < 2; ++q)                                                       \
      gload16(kbase + (size_t)(T) * 8192 + ksrc[q] * 8,                               \
              (char*)(&KD[0][0]) + q * 8192 + wave * 1024);                           \
    _Pragma("unroll")                                                                 \
    for (int q = 0; q < 2; ++q)                                                       \
      gload16(vlane + (size_t)q * 262144 + (T) * 64,                                  \
              (char*)(&VD[0][0]) + q * 8192 + wave * 1024);                           \
  } while (0)

    const int krow = jh * 32 + l31;
    const int ksw  = l31 & 15;                    // krow & 15
    const int vk   = (l31 & 7) ^ (l31 >> 3);      // V key base (^ (ct<<2) per ct)
    const int irow = ih * 32 + l31;               // this lane's P row
    const int pkey = (irow ^ (irow >> 3)) & 7;    // P key (masked to 3 bits)

    // prologue: prefetch tile 0 -> buf0 (drained at first barrier; one-time cost)
    STAGE(0, K0, V0);

#define ATTN_ITER(IT, KR, VR, KP, VP)                                                 \
  do {                                                                                \
    __syncthreads(); /* A: buf(IT) loads visible; prev iter's LDS reads done */       \
    if ((IT) < 15) STAGE((IT) + 1, KP, VP);   /* drains at NEXT barrier A: hidden */  \
    f32x16 s; /* S^T quadrant: row j=(r&3)+8(r>>2)+4h (+jh*32), col i (lane) */       \
    _Pragma("unroll")                                                                 \
    for (int e = 0; e < 16; ++e) s[e] = 0.f;                                          \
    _Pragma("unroll")                                                                 \
    for (int ks = 0; ks < 8; ++ks) {                                                  \
      short8 kf = *(const short8*)&KR[krow][((ks * 2 + h) ^ ksw) << 3];               \
      s = MFMA32(kf, qf[ks], s);                                                      \
    }                                                                                 \
    float pv[16]; /* max-free base-2 softmax */                                       \
    _Pragma("unroll")                                                                 \
    for (int e = 0; e < 16; ++e) pv[e] = EXP2(fminf(s[e], 30.f));                     \
    l_run += (((pv[0] + pv[1]) + (pv[2] + pv[3])) +                                   \
              ((pv[4] + pv[5]) + (pv[6] + pv[7]))) +                                  \
             (((pv[8] + pv[9]) + (pv[10] + pv[11])) +                                 \
              ((pv[12] + pv[13]) + (pv[14] + pv[15])));                               \
    {                                                                                 \
      char* prow = (char*)&P_lds[irow][0];                                            \
      _Pragma("unroll")                                                               \
      for (int rr = 0; rr < 4; ++rr) {                                                \
        uint2 pk;                                                                     \
        pk.x = cvtpk(pv[rr * 4 + 0], pv[rr * 4 + 1]);                                 \
        pk.y = cvtpk(pv[rr * 4 + 2], pv[rr * 4 + 3]);                                 \
        *(uint2*)(prow + ((((jh << 2) + rr) ^ pkey) << 4) + (h << 3)) = pk;           \
      }                                                                               \
    }                                                                                 \
    __syncthreads(); /* B: P visible */                                               \
    _Pragma("unroll")                                                                 \
    for (int ks = 0; ks < 4; ++ks) {                                                  \
      short8 pf = *(const short8*)((const char*)&P_lds[irow][0] +                     \
                                   (((ks * 2 + h) ^ pkey) << 4));                     \
      _Pragma("unroll")                                                               \
      for (int ct = 0; ct < 2; ++ct) {                                                \
        short8 vf = *(const short8*)&VR[jh * 64 + ct * 32 + l31]                      \
                        [((ks * 2 + h) ^ vk ^ (ct << 2)) << 3];                       \
        acc[ct] = MFMA32(pf, vf, acc[ct]);                                            \
      }                                                                               \
    }                                                                                 \
  } while (0)

    for (int ib = 0; ib < 8; ++ib) {
        ATTN_ITER(ib * 2,     K0, V0, K1, V1);
        ATTN_ITER(ib * 2 + 1, K1, V1, K0, V0);
    }
#undef ATTN_ITER
#undef STAGE

    // epilogue: combine row sums (h via shfl, jh via LDS overlay on K0), store
    __syncthreads();                                 // all loop LDS reads done
    float* Lp = (float*)(&K0[0][0]);                 // [jh*128 + i], 1 KB of K0
    float l2 = l_run + __shfl_xor(l_run, 32);        // h-halves: disjoint j, same i
    if (h == 0) Lp[jh * 128 + irow] = l2;
    __syncthreads();

    float rl[16];
#pragma unroll
    for (int r = 0; r < 16; ++r) {
        int il = (r & 3) + ((r >> 2) << 3) + (h << 2);
        rl[r] = 1.0f / (Lp[ih * 32 + il] + Lp[128 + ih * 32 + il]);
    }
#pragma unroll
    for (int ct = 0; ct < 2; ++ct)
#pragma unroll
        for (int r = 0; r < 16; ++r) {
            int row = ih * 32 + (r & 3) + ((r >> 2) << 3) + (h << 2);
            // o_part layout: [b][i 4096][chunk 4][c 128]
            o_part[(((size_t)(b * 4096 + i0 + row) * 4 + chunk) << 7) +
                   jh * 64 + ct * 32 + l31] = f2bf(acc[ct][r] * rl[r]);
        }
    if (tid < 128) {
        // ml layout: [b][i 4096][chunk 4]
        ml[(b * 4096 + i0 + tid) * 4 + chunk] = __log2f(Lp[tid] + Lp[128 + tid]);
    }
}

// ---------------- Kernel 4: merge partials + proj GEMM + bias + residual ----------
__global__ __launch_bounds__(256) void k_merge_proj(const unsigned short* __restrict__ o_part,
                                                    const float* __restrict__ ml,
                                                    const float* __restrict__ x,
                                                    const unsigned short* __restrict__ wp,
                                                    const float* __restrict__ proj_b,
                                                    float* __restrict__ out) {
    __shared__ unsigned short O_lds[64][136];
    __shared__ float wgt[64][4];
    const int tid  = threadIdx.x;
    const int b    = blockIdx.x >> 6;
    const int tile = blockIdx.x & 63;
    const int i0   = tile << 6;
    const int lane = tid & 63, wave = tid >> 6;
    const int l15  = lane & 15, q4 = lane >> 4;

    if (tid < 64) {
        size_t mb = (size_t)(b * 4096 + i0 + tid) * 4;
        float m0 = ml[mb + 0], m1 = ml[mb + 1], m2 = ml[mb + 2], m3 = ml[mb + 3];
        float M = fmaxf(fmaxf(m0, m1), fmaxf(m2, m3));
        float w0 = EXP2(m0 - M), w1 = EXP2(m1 - M), w2 = EXP2(m2 - M), w3 = EXP2(m3 - M);
        float rW = 1.0f / (w0 + w1 + w2 + w3);
        wgt[tid][0] = w0 * rW; wgt[tid][1] = w1 * rW;
        wgt[tid][2] = w2 * rW; wgt[tid][3] = w3 * rW;
    }
    __syncthreads();

    {   // weighted merge: thread t -> row n=t>>2, 32-c quarter q=t&3
        int n = tid >> 2, q = tid & 3;
        float w[4];
#pragma unroll
        for (int ch = 0; ch < 4; ++ch) w[ch] = wgt[n][ch];
        size_t rbase = ((size_t)(b * 4096 + i0 + n) * 4) << 7;   // row's 4 partials
#pragma unroll
        for (int g = 0; g < 4; ++g) {             // 8 c per group
            float acc[8];
#pragma unroll
            for (int e = 0; e < 8; ++e) acc[e] = 0.f;
#pragma unroll
            for (int ch = 0; ch < 4; ++ch) {
                const unsigned short* p = o_part + rbase + (ch << 7) + q * 32 + g * 8;
                uint4 v = *(const uint4*)p;
                float wc = w[ch];
                acc[0] += wc * bf2f(v.x & 0xFFFF); acc[1] += wc * bf2f(v.x >> 16);
                acc[2] += wc * bf2f(v.y & 0xFFFF); acc[3] += wc * bf2f(v.y >> 16);
                acc[4] += wc * bf2f(v.z & 0xFFFF); acc[5] += wc * bf2f(v.z >> 16);
                acc[6] += wc * bf2f(v.w & 0xFFFF); acc[7] += wc * bf2f(v.w >> 16);
            }
            uint4 pk;
            pk.x = (unsigned int)f2bf(acc[0]) | ((unsigned int)f2bf(acc[1]) << 16);
            pk.y = (unsigned int)f2bf(acc[2]) | ((unsigned int)f2bf(acc[3]) << 16);
            pk.z = (unsigned int)f2bf(acc[4]) | ((unsigned int)f2bf(acc[5]) << 16);
            pk.w = (unsigned int)f2bf(acc[6]) | ((unsigned int)f2bf(acc[7]) << 16);
            *(uint4*)&O_lds[n][q * 32 + g * 8] = pk;
        }
    }
    __syncthreads();

    // proj GEMM: out[o][n] = sum_c proj_w[o][c] * O[n][c] + proj_b + x
    short8 bfrag[4][4];
#pragma unroll
    for (int nt = 0; nt < 4; ++nt)
#pragma unroll
        for (int ks = 0; ks < 4; ++ks)
            bfrag[nt][ks] = *(const short8*)&O_lds[nt * 16 + l15][ks * 32 + q4 * 8];

#pragma unroll
    for (int ot = 0; ot < 2; ++ot) {
        int o0 = wave * 32 + ot * 16;
        short8 af[4];
#pragma unroll
        for (int ks = 0; ks < 4; ++ks)
            af[ks] = ldg8(wp + (size_t)(o0 + l15) * 128 + ks * 32 + q4 * 8);
        float pb[4];
#pragma unroll
        for (int r = 0; r < 4; ++r) pb[r] = proj_b[o0 + q4 * 4 + r];

#pragma unroll
        for (int nt = 0; nt < 4; ++nt) {
            f32x4 acc = {0.f, 0.f, 0.f, 0.f};
#pragma unroll
            for (int ks = 0; ks < 4; ++ks)
                acc = MFMA_BF16(af[ks], bfrag[nt][ks], acc);
#pragma unroll
            for (int r = 0; r < 4; ++r) {
                size_t idx = ((size_t)(b * 128 + o0 + q4 * 4 + r) << 12) + i0 + nt * 16 + l15;
                out[idx] = x[idx] + acc[r] + pb[r];
            }
        }
    }
}

// ---------------- launch ----------------
extern "C" void kernel_launch(void* const* d_in, const int* in_sizes, int n_in,
                              void* d_out, int out_size, void* d_ws, size_t ws_size,
                              hipStream_t stream) {
    const float* x      = (const float*)d_in[0];
    const float* gn_w   = (const float*)d_in[1];
    const float* gn_b   = (const float*)d_in[2];
    const float* qkv_w  = (const float*)d_in[3];
    const float* qkv_b  = (const float*)d_in[4];
    const float* proj_w = (const float*)d_in[5];
    const float* proj_b = (const float*)d_in[6];
    float* out = (float*)d_out;

    char* ws = (char*)d_ws;
    float* sums           = (float*)ws;                              // 512 B (zeroed below)
    unsigned short* wq    = (unsigned short*)(ws + 4096);            // 96 KB
    unsigned short* wp    = (unsigned short*)(ws + 4096 + 98304);    // 32 KB
    unsigned short* q_ws  = (unsigned short*)(ws + ((size_t)1  << 20));  // 8 MB
    unsigned short* k_ws  = (unsigned short*)(ws + ((size_t)9  << 20));  // 8 MB
    unsigned short* v_ws  = (unsigned short*)(ws + ((size_t)17 << 20));  // 8 MB
    unsigned short* o_part= (unsigned short*)(ws + ((size_t)25 << 20));  // 32 MB
    float* ml             = (float*)(ws + ((size_t)57 << 20));           // 512 KB

    hipMemsetAsync(sums, 0, 512, stream);
    k_pre<<<1088, 256, 0, stream>>>(x, sums, qkv_w, proj_w, wq, wp);
    k_qkv<<<512, 256, 0, stream>>>(x, sums, gn_w, gn_b, wq, qkv_b, q_ws, k_ws, v_ws);
    k_attn_part<<<1024, 512, 0, stream>>>(q_ws, k_ws, v_ws, o_part, ml);
    k_merge_proj<<<512, 256, 0, stream>>>(o_part, ml, x, wp, proj_b, out);
}